// Round 2
// baseline (158.104 us; speedup 1.0000x reference)
//
#include <hip/hip_runtime.h>

#define B_SZ 1024
#define F_SZ 32
#define D_SZ 128
#define FD   (F_SZ * D_SZ)      // 4096 shorts per b-row of feature
#define NPAIR 496               // F*(F-1)/2

typedef __bf16 bf16x8 __attribute__((ext_vector_type(8)));
typedef __bf16 bf16x4 __attribute__((ext_vector_type(4)));
typedef float floatx4 __attribute__((ext_vector_type(4)));
typedef unsigned short u16x8 __attribute__((ext_vector_type(8)));

__device__ __forceinline__ unsigned short f2bf(float f) {
  // round-to-nearest-even fp32 -> bf16 (no NaN inputs here)
  unsigned u = __float_as_uint(f);
  u += 0x7fffu + ((u >> 16) & 1u);
  return (unsigned short)(u >> 16);
}

__device__ __forceinline__ float bf2f(unsigned short h) {
  return __uint_as_float(((unsigned)h) << 16);
}

__device__ __forceinline__ void gload_lds16(const void* g, void* l) {
  // async 16B/lane global->LDS; LDS dest = wave-uniform base + lane*16
  __builtin_amdgcn_global_load_lds(
      (const __attribute__((address_space(1))) unsigned int*)g,
      (__attribute__((address_space(3))) unsigned int*)l,
      16, 0, 0);
}

// ---------------- fused prep: one dispatch, 3 sections by blockIdx ----------
// [0, 992):        Z -> sigmoid/stretch/clip -> bf16, transposed [e][d],
//                  XOR-swizzled in 8-short groups (group g stored at g^(e&7))
//                  so main can stage LINEAR global_load_lds + conflict-free reads.
//                  2 blocks per pair (d-halves) for parallelism.
// [992, 2016):     feature fp32 -> bf16 hi + bf16 residual lo (fj near-fp32).
// [2016, 2272):    zero the output (diagonal + lower triangle stay 0).
__global__ __launch_bounds__(256)
void prep_kernel(const float* __restrict__ feat, const float* __restrict__ mat,
                 unsigned short* __restrict__ featHi, unsigned short* __restrict__ featLo,
                 unsigned short* __restrict__ ZT, float* __restrict__ out) {
  const int bid = blockIdx.x, t = threadIdx.x;
  __shared__ unsigned short tr[128 * 72];   // [e][d-half], 144B rows (16B-aligned)

  if (bid < 2 * NPAIR) {
    const int pid = bid >> 1, h = bid & 1, d0 = h * 64;
    int p = pid, i = 0;
    while (p >= F_SZ - 1 - i) { p -= F_SZ - 1 - i; ++i; }
    const int j = i + 1 + p;
    const float* zp = mat + (((size_t)i * F_SZ + j) * (size_t)(D_SZ * D_SZ));
    #pragma unroll
    for (int it = 0; it < 8; ++it) {
      int idx4 = it * 256 + t;               // 2048 float4 groups (64 d x 32 e4)
      int dl = idx4 >> 5, e4 = (idx4 & 31) * 4;
      const float4 v = *(const float4*)(zp + (size_t)(d0 + dl) * D_SZ + e4);
      float zs[4] = {v.x, v.y, v.z, v.w};
      #pragma unroll
      for (int c = 0; c < 4; ++c) {
        float s = 1.0f / (1.0f + __expf(-zs[c]));
        float z = fminf(1.0f, fmaxf(0.0f, fmaf(s, 1.2f, -0.1f)));
        tr[(e4 + c) * 72 + dl] = f2bf(z);    // transposed store
      }
    }
    __syncthreads();
    #pragma unroll
    for (int it = 0; it < 4; ++it) {
      int G = it * 256 + t;                  // 1024: e(128) x out-group gl(8)
      int e = G >> 3, gl = G & 7;
      int gs = gl ^ (e & 7);                 // source d-local 8-short group
      u16x8 v = *(const u16x8*)&tr[e * 72 + gs * 8];
      *(u16x8*)&ZT[(size_t)pid * (D_SZ * D_SZ) + e * 128 + d0 + gl * 8] = v;
    }
  } else if (bid < 2 * NPAIR + 1024) {
    int idx = (bid - 2 * NPAIR) * 256 + t;   // 262144 threads x 16 floats
    const float4* f4 = (const float4*)feat + (size_t)idx * 4;
    #pragma unroll
    for (int q = 0; q < 2; ++q) {
      float4 a = f4[q * 2], b = f4[q * 2 + 1];
      float vs[8] = {a.x, a.y, a.z, a.w, b.x, b.y, b.z, b.w};
      u16x8 hi, lo;
      #pragma unroll
      for (int c = 0; c < 8; ++c) {
        unsigned short hh = f2bf(vs[c]);
        hi[c] = hh;
        lo[c] = f2bf(vs[c] - bf2f(hh));      // exact residual, then bf16
      }
      *(u16x8*)&featHi[(size_t)idx * 16 + q * 8] = hi;
      *(u16x8*)&featLo[(size_t)idx * 16 + q * 8] = lo;
    }
  } else {
    int idx = (bid - (2 * NPAIR + 1024)) * 256 + t;  // 65536 threads x 16 f32
    float4* o4 = (float4*)out + (size_t)idx * 4;
    float4 z = {0.f, 0.f, 0.f, 0.f};
    o4[0] = z; o4[1] = z; o4[2] = z; o4[3] = z;
  }
}

// ---------------- main: one block per (pair, 128-row split); 4 waves --------
// W-orientation: per wave W[e=128, b=32] = Z^T @ f_i^T via MFMA (A=Z from LDS,
// B=f_i direct global bf16). Then out[b] = diag(fj @ W) via a SECOND MFMA:
// W's C-layout and the needed B-frag layout share b=lane&15, so the remap is a
// per-wave private 4KB LDS round-trip. fj = bf16 hi + lo (near-fp32).
// ONE barrier per block; no cross-wave reduction; plain stores.
__global__ __launch_bounds__(256, 3)
void interaction_pair_kernel(const unsigned short* __restrict__ featHi,
                             const unsigned short* __restrict__ featLo,
                             const unsigned short* __restrict__ ZT,
                             float* __restrict__ out) {
  __shared__ unsigned short sZ[128 * 128];   // 32KB swizzled [e][d']
  __shared__ unsigned short sW[4 * 2048];    // 4KB per wave: W n-tile [16 b][128 e]

  const int t    = threadIdx.x;
  const int w    = t >> 6;
  const int lane = t & 63;
  const int l15  = lane & 15;
  const int quad = lane >> 4;
  const int swz  = (l15 & 7) << 4;           // byte-level 16B-group XOR swizzle

  const int pid   = blockIdx.x >> 3;
  const int split = blockIdx.x & 7;
  int p = pid, i = 0;
  while (p >= F_SZ - 1 - i) { p -= F_SZ - 1 - i; ++i; }
  const int j = i + 1 + p;

  // ---- stage sZ: 32KB linear async copy (content pre-swizzled by prep) ----
  {
    const char* src = (const char*)(ZT + (size_t)pid * (D_SZ * D_SZ));
    #pragma unroll
    for (int it = 0; it < 8; ++it) {
      int off = it * 4096 + w * 1024;        // wave-uniform LDS offset
      gload_lds16(src + off + lane * 16, (char*)sZ + off);
    }
  }
  __syncthreads();   // the ONLY barrier

  const int rbase = split * 128 + w * 32;    // wave's 32 b-rows

  // ---- stage 1: W[e, b] accumulate; acc[m][n]: m = e-tile(8), n = b-tile(2)
  floatx4 acc[8][2];
  #pragma unroll
  for (int m = 0; m < 8; ++m) {
    acc[m][0] = (floatx4){0.f, 0.f, 0.f, 0.f};
    acc[m][1] = (floatx4){0.f, 0.f, 0.f, 0.f};
  }

  #pragma unroll
  for (int k0 = 0; k0 < 4; ++k0) {
    const int dq = k0 * 32 + quad * 8;
    // B-frags (f_i): lane&15 = b-col, quad = d-chunk -> direct global b128
    bf16x8 b0f = *(const bf16x8*)&featHi[(size_t)(rbase +      l15) * FD + i * D_SZ + dq];
    bf16x8 b1f = *(const bf16x8*)&featHi[(size_t)(rbase + 16 + l15) * FD + i * D_SZ + dq];
    #pragma unroll
    for (int m = 0; m < 8; ++m) {
      // A-frag (Z^T): lane&15 = e-row; swizzled LDS read (conflict-free)
      const int e = m * 16 + l15;
      bf16x8 za = *(const bf16x8*)((const char*)sZ + e * 256 + ((2 * dq) ^ swz));
      acc[m][0] = __builtin_amdgcn_mfma_f32_16x16x32_bf16(za, b0f, acc[m][0], 0, 0, 0);
      acc[m][1] = __builtin_amdgcn_mfma_f32_16x16x32_bf16(za, b1f, acc[m][1], 0, 0, 0);
    }
  }

  // ---- stage 2: out[b] = diag( fj @ W ), fj = hi + lo ----
  char* wb = (char*)(sW + w * 2048);         // per-wave private region
  #pragma unroll
  for (int n = 0; n < 2; ++n) {
    // pack this n-tile of W to bf16 and write [b][e] swizzled (b64 writes)
    #pragma unroll
    for (int m = 0; m < 8; ++m) {
      floatx4 c = acc[m][n];
      bf16x4 v = {(__bf16)c[0], (__bf16)c[1], (__bf16)c[2], (__bf16)c[3]};
      const int e0 = m * 16 + quad * 4;      // C-layout: row(e) = quad*4 + reg
      *(bf16x4*)(wb + l15 * 256 + ((2 * e0) ^ swz)) = v;
    }
    const int row = rbase + n * 16 + l15;
    const unsigned short* fj_h = featHi + (size_t)row * FD + j * D_SZ;
    const unsigned short* fj_l = featLo + (size_t)row * FD + j * D_SZ;
    floatx4 g = (floatx4){0.f, 0.f, 0.f, 0.f};
    #pragma unroll
    for (int k0 = 0; k0 < 4; ++k0) {
      // B-frag (W): lane&15 = b-col, quad = e-chunk; same-wave RAW via lgkmcnt
      bf16x8 wf = *(const bf16x8*)(wb + l15 * 256 + ((k0 * 64 + quad * 16) ^ swz));
      bf16x8 ah = *(const bf16x8*)(fj_h + k0 * 32 + quad * 8);
      bf16x8 al = *(const bf16x8*)(fj_l + k0 * 32 + quad * 8);
      g = __builtin_amdgcn_mfma_f32_16x16x32_bf16(ah, wf, g, 0, 0, 0);
      g = __builtin_amdgcn_mfma_f32_16x16x32_bf16(al, wf, g, 0, 0, 0);
    }
    // diagonal: G[row=quad*4+r, col=l15]; diag held where quad == l15>>2
    if ((l15 >> 2) == quad) {
      const int r = l15 & 3;
      float val = g[r];
      out[(size_t)row * (F_SZ * F_SZ) + (size_t)i * F_SZ + j] = val;
    }
  }
}

extern "C" void kernel_launch(void* const* d_in, const int* in_sizes, int n_in,
                              void* d_out, int out_size, void* d_ws, size_t ws_size,
                              hipStream_t stream) {
  const float* feat = (const float*)d_in[0];   // [B, F, D] fp32
  const float* mat  = (const float*)d_in[1];   // [F, F, D, D] fp32
  float* out = (float*)d_out;                  // [B, F, F] fp32

  unsigned short* featHi = (unsigned short*)d_ws;                      // 8.4MB
  unsigned short* featLo = featHi + (size_t)B_SZ * F_SZ * D_SZ;        // 8.4MB
  unsigned short* ZT     = featLo + (size_t)B_SZ * F_SZ * D_SZ;        // 15.9MB

  const int prep_grid = 2 * NPAIR + 1024 + 256;   // 2272
  prep_kernel<<<dim3(prep_grid), dim3(256), 0, stream>>>(feat, mat, featHi, featLo, ZT, out);
  interaction_pair_kernel<<<dim3(NPAIR * 8), dim3(256), 0, stream>>>(featHi, featLo, ZT, out);
}

// Round 3
// 154.248 us; speedup vs baseline: 1.0250x; 1.0250x over previous
//
#include <hip/hip_runtime.h>

#define B_SZ 1024
#define F_SZ 32
#define D_SZ 128
#define FD   4096               // shorts (or floats) per b-row of feature
#define NPAIR 496               // F*(F-1)/2

typedef __bf16 bf16x8 __attribute__((ext_vector_type(8)));
typedef float floatx4 __attribute__((ext_vector_type(4)));
typedef unsigned short u16x8 __attribute__((ext_vector_type(8)));

__device__ __forceinline__ unsigned short f2bf(float f) {
  // round-to-nearest-even fp32 -> bf16 (no NaN inputs here)
  unsigned u = __float_as_uint(f);
  u += 0x7fffu + ((u >> 16) & 1u);
  return (unsigned short)(u >> 16);
}

__device__ __forceinline__ bf16x8 as_bf16x8(floatx4 v) {
  union { floatx4 f; bf16x8 b; } u; u.f = v; return u.b;
}

__device__ __forceinline__ void gload_lds16(const void* g, void* l) {
  // async 16B/lane global->LDS; LDS dest = wave-uniform base + lane*16
  __builtin_amdgcn_global_load_lds(
      (const __attribute__((address_space(1))) unsigned int*)g,
      (__attribute__((address_space(3))) unsigned int*)l,
      16, 0, 0);
}

// ---------------- fused prep: one dispatch, 3 sections by blockIdx ----------
// [0, 992):        Z -> sigmoid/stretch/clip -> bf16, transposed [e][d],
//                  XOR-swizzled in 8-short groups (group g stored at g^(e&7))
//                  so main can stage LINEAR global_load_lds + conflict-free
//                  ds_read_b128. 2 blocks per pair (d-halves).
// [992, 2016):     feature fp32 -> bf16 (stage-1 operand; epilogue uses fp32).
// [2016, 2272):    zero the output (diagonal + lower triangle stay 0).
__global__ __launch_bounds__(256)
void prep_kernel(const float* __restrict__ feat, const float* __restrict__ mat,
                 unsigned short* __restrict__ featB,
                 unsigned short* __restrict__ ZT, float* __restrict__ out) {
  const int bid = blockIdx.x, t = threadIdx.x;
  __shared__ unsigned short tr[128 * 72];   // [e][d-half], 144B rows (16B-aligned)

  if (bid < 2 * NPAIR) {
    const int pid = bid >> 1, h = bid & 1, d0 = h * 64;
    int p = pid, i = 0;
    while (p >= F_SZ - 1 - i) { p -= F_SZ - 1 - i; ++i; }
    const int j = i + 1 + p;
    const float* zp = mat + (((size_t)i * F_SZ + j) * (size_t)(D_SZ * D_SZ));
    #pragma unroll
    for (int it = 0; it < 8; ++it) {
      int idx4 = it * 256 + t;               // 2048 float4 groups (64 d x 32 e4)
      int dl = idx4 >> 5, e4 = (idx4 & 31) * 4;
      const float4 v = *(const float4*)(zp + (size_t)(d0 + dl) * D_SZ + e4);
      float zs[4] = {v.x, v.y, v.z, v.w};
      #pragma unroll
      for (int c = 0; c < 4; ++c) {
        float s = 1.0f / (1.0f + __expf(-zs[c]));
        float z = fminf(1.0f, fmaxf(0.0f, fmaf(s, 1.2f, -0.1f)));
        tr[(e4 + c) * 72 + dl] = f2bf(z);    // transposed store
      }
    }
    __syncthreads();
    #pragma unroll
    for (int it = 0; it < 4; ++it) {
      int G = it * 256 + t;                  // 1024: e(128) x out-group gl(8)
      int e = G >> 3, gl = G & 7;
      int gs = gl ^ (e & 7);                 // source d-local 8-short group
      u16x8 v = *(const u16x8*)&tr[e * 72 + gs * 8];
      *(u16x8*)&ZT[(size_t)pid * (D_SZ * D_SZ) + e * 128 + d0 + gl * 8] = v;
    }
  } else if (bid < 2 * NPAIR + 1024) {
    int idx = (bid - 2 * NPAIR) * 256 + t;   // 262144 threads x 16 floats
    const float4* f4 = (const float4*)feat + (size_t)idx * 4;
    #pragma unroll
    for (int q = 0; q < 2; ++q) {
      float4 a = f4[q * 2], b = f4[q * 2 + 1];
      float vs[8] = {a.x, a.y, a.z, a.w, b.x, b.y, b.z, b.w};
      u16x8 hi;
      #pragma unroll
      for (int c = 0; c < 8; ++c) hi[c] = f2bf(vs[c]);
      *(u16x8*)&featB[(size_t)idx * 16 + q * 8] = hi;
    }
  } else {
    int idx = (bid - (2 * NPAIR + 1024)) * 256 + t;  // 65536 threads x 16 f32
    float4* o4 = (float4*)out + (size_t)idx * 4;
    float4 z = {0.f, 0.f, 0.f, 0.f};
    o4[0] = z; o4[1] = z; o4[2] = z; o4[3] = z;
  }
}

// ---------------- main: one block per (pair, 512-row half); 4 waves ----------
// W-orientation: acc[m] = MFMA(A = Z^T e-rows from regs, B = f_i b-cols from
// global bf16) -> C[row=e, col=b=lane&15]. Reduction axis (e) is LANE-LOCAL:
// epilogue is 8 float4 fp32 f_j loads + 32 FMAs + 2 shuffles per phase.
// Z frags read from LDS ONCE per block and pinned in VGPRs via asm; 4 b-tile
// passes amortize the stage. ONE barrier per block; tile loop barrier-free.
__global__ __launch_bounds__(256, 2)
void interaction_pair_kernel(const float* __restrict__ feat,
                             const unsigned short* __restrict__ featB,
                             const unsigned short* __restrict__ ZT,
                             float* __restrict__ out) {
  __shared__ unsigned short sZ[128 * 128];   // 32KB swizzled [e][d']

  const int t    = threadIdx.x;
  const int w    = t >> 6;
  const int lane = t & 63;
  const int l15  = lane & 15;
  const int quad = lane >> 4;
  const int swz  = (l15 & 7) << 4;           // byte-level 16B-group XOR swizzle

  const int pid   = blockIdx.x >> 1;
  const int split = blockIdx.x & 1;
  int p = pid, i = 0;
  while (p >= F_SZ - 1 - i) { p -= F_SZ - 1 - i; ++i; }
  const int j = i + 1 + p;

  // ---- stage sZ: 32KB linear async copy (content pre-swizzled by prep) ----
  {
    const char* src = (const char*)(ZT + (size_t)pid * (D_SZ * D_SZ));
    #pragma unroll
    for (int it = 0; it < 8; ++it) {
      int off = it * 4096 + w * 1024;        // wave-uniform LDS offset
      gload_lds16(src + off + lane * 16, (char*)sZ + off);
    }
  }
  __syncthreads();   // the ONLY barrier

  // ---- Z A-frags -> registers, once per block; pin so they stay there ----
  // za[k0][m] = Z^T[e = m*16 + l15, d = k0*32 + quad*8 .. +7]
  floatx4 zr[4][8];
  #pragma unroll
  for (int k0 = 0; k0 < 4; ++k0)
    #pragma unroll
    for (int m = 0; m < 8; ++m)
      zr[k0][m] = *(const floatx4*)((const char*)sZ + (m * 16 + l15) * 256 +
                                    ((k0 * 64 + quad * 16) ^ swz));
  #pragma unroll
  for (int k0 = 0; k0 < 4; ++k0)
    #pragma unroll
    for (int m = 0; m < 8; ++m)
      asm volatile("" : "+v"(zr[k0][m]));    // opaque def: no remat, no re-read

  #pragma unroll 1
  for (int pass = 0; pass < 4; ++pass) {
    const int rbase = split * 512 + pass * 128 + w * 32;  // wave's 32 b-rows

    #pragma unroll
    for (int n = 0; n < 2; ++n) {
      const int row = rbase + n * 16 + l15;

      // stage 1: acc[m] += Z^T @ f_i^T for this 16-b group (64 MFMA per pass)
      floatx4 a8[8];
      #pragma unroll
      for (int m = 0; m < 8; ++m) a8[m] = (floatx4){0.f, 0.f, 0.f, 0.f};

      const unsigned short* bp = featB + (size_t)row * FD + i * D_SZ + quad * 8;
      #pragma unroll
      for (int k0 = 0; k0 < 4; ++k0) {
        bf16x8 bf = *(const bf16x8*)(bp + k0 * 32);   // B-frag: f_i[b, d-chunk]
        #pragma unroll
        for (int m = 0; m < 8; ++m)
          a8[m] = __builtin_amdgcn_mfma_f32_16x16x32_bf16(
              as_bf16x8(zr[k0][m]), bf, a8[m], 0, 0, 0);
      }

      // epilogue: out[b] = sum_e W[e,b] * f_j[b,e]; e is lane-local
      // C-layout: col(b) = l15, row(e within m-tile) = quad*4 + reg
      float pl = 0.f;
      const float* fp = feat + (size_t)row * FD + j * D_SZ + quad * 4;
      #pragma unroll
      for (int m = 0; m < 8; ++m) {
        const float4 f4 = *(const float4*)(fp + m * 16);
        pl += a8[m][0] * f4.x + a8[m][1] * f4.y + a8[m][2] * f4.z + a8[m][3] * f4.w;
      }
      pl += __shfl_xor(pl, 16, 64);          // reduce over quad
      pl += __shfl_xor(pl, 32, 64);
      if (quad == 0)
        out[(size_t)row * (F_SZ * F_SZ) + (size_t)i * F_SZ + j] = pl;
    }
  }
}

extern "C" void kernel_launch(void* const* d_in, const int* in_sizes, int n_in,
                              void* d_out, int out_size, void* d_ws, size_t ws_size,
                              hipStream_t stream) {
  const float* feat = (const float*)d_in[0];   // [B, F, D] fp32
  const float* mat  = (const float*)d_in[1];   // [F, F, D, D] fp32
  float* out = (float*)d_out;                  // [B, F, F] fp32

  unsigned short* featB = (unsigned short*)d_ws;                   // 8.4MB bf16
  unsigned short* ZT    = featB + (size_t)B_SZ * F_SZ * D_SZ;      // 16.3MB bf16

  const int prep_grid = 2 * NPAIR + 1024 + 256;   // 2272
  prep_kernel<<<dim3(prep_grid), dim3(256), 0, stream>>>(feat, mat, featB, ZT, out);
  interaction_pair_kernel<<<dim3(NPAIR * 2), dim3(256), 0, stream>>>(feat, featB, ZT, out);
}